// Round 1
// baseline (616.408 us; speedup 1.0000x reference)
//
#include <hip/hip_runtime.h>

#define NNODES 50000
#define NEDGES 200000

typedef short  bf16x8 __attribute__((ext_vector_type(8)));
typedef float  f32x4  __attribute__((ext_vector_type(4)));
typedef unsigned int u32x4 __attribute__((ext_vector_type(4)));

__device__ __forceinline__ unsigned short f2bf(float f) {
    union { float f; unsigned int u; } c; c.f = f;
    unsigned int r = c.u + 0x7fffu + ((c.u >> 16) & 1u);
    return (unsigned short)(r >> 16);
}
__device__ __forceinline__ float bf2f(unsigned short h) {
    union { unsigned int u; float f; } c; c.u = ((unsigned int)h) << 16;
    return c.f;
}

// ---------------- CSR build ----------------
__global__ void k_count(const int* __restrict__ ei, int* __restrict__ deg) {
    int e = blockIdx.x * 256 + threadIdx.x;
    if (e < NEDGES) atomicAdd(&deg[ei[NEDGES + e]], 1);
}

__global__ __launch_bounds__(1024) void k_scan(const int* __restrict__ deg,
                                               int* __restrict__ row_start,
                                               int* __restrict__ cursor) {
    __shared__ int part[1024];
    int t = threadIdx.x;
    const int C = (NNODES + 1023) / 1024;  // 49
    int base = t * C;
    int s = 0;
    for (int i = 0; i < C; ++i) { int idx = base + i; if (idx < NNODES) s += deg[idx]; }
    part[t] = s;
    __syncthreads();
    for (int off = 1; off < 1024; off <<= 1) {
        int v = (t >= off) ? part[t - off] : 0;
        __syncthreads();
        part[t] += v;
        __syncthreads();
    }
    int run = part[t] - s;  // exclusive prefix for this chunk
    for (int i = 0; i < C; ++i) {
        int idx = base + i;
        if (idx < NNODES) { row_start[idx] = run; cursor[idx] = run; run += deg[idx]; }
    }
    if (t == 1023) row_start[NNODES] = part[1023];
}

__global__ void k_scatter(const int* __restrict__ ei, int* __restrict__ cursor,
                          int* __restrict__ srcs) {
    int e = blockIdx.x * 256 + threadIdx.x;
    if (e < NEDGES) {
        int d = ei[NEDGES + e];
        int p = atomicAdd(&cursor[d], 1);
        srcs[p] = ei[e];
    }
}

// ---------------- weight transposes (bf16) ----------------
// Bt1[n*1024+k] = k<512 ? W1_rel[k][n] : W1_root[k-512][n]   (n<256)
__global__ void k_bt1(const float* __restrict__ Wrel, const float* __restrict__ Wroot,
                      unsigned short* __restrict__ Bt) {
    int i = blockIdx.x * 256 + threadIdx.x;
    if (i >= 256 * 1024) return;
    int n = i >> 10, k = i & 1023;
    float v = (k < 512) ? Wrel[k * 256 + n] : Wroot[(k - 512) * 256 + n];
    Bt[i] = f2bf(v);
}
// Bt2[n*512+k] = k<256 ? W2_rel[k][n] : W2_root[k-256][n]   (n<64)
__global__ void k_bt2(const float* __restrict__ Wrel, const float* __restrict__ Wroot,
                      unsigned short* __restrict__ Bt) {
    int i = blockIdx.x * 256 + threadIdx.x;
    if (i >= 64 * 512) return;
    int n = i >> 9, k = i & 511;
    float v = (k < 256) ? Wrel[k * 64 + n] : Wroot[(k - 256) * 64 + n];
    Bt[i] = f2bf(v);
}

// ---------------- x -> bf16 into Abuf1 cols 512..1023 ----------------
__global__ void k_xcast(const float* __restrict__ x, unsigned short* __restrict__ Abuf1) {
    int i = blockIdx.x * 256 + threadIdx.x;  // over NNODES*128
    if (i >= NNODES * 128) return;
    int n = i >> 7, c4 = (i & 127) * 4;
    float4 v = *(const float4*)(x + n * 512 + c4);
    ushort4 o;
    o.x = f2bf(v.x); o.y = f2bf(v.y); o.z = f2bf(v.z); o.w = f2bf(v.w);
    *(ushort4*)(Abuf1 + n * 1024 + 512 + c4) = o;
}

// ---------------- softmax aggregation (layer 1) ----------------
// block = one dst node, 256 threads, 2 features each + index feature
__global__ __launch_bounds__(256) void k_agg1(const float* __restrict__ x,
                                              const int* __restrict__ row_start,
                                              const int* __restrict__ srcs,
                                              unsigned short* __restrict__ Abuf1,
                                              float* __restrict__ aggidx) {
    int n = blockIdx.x;
    int t = threadIdx.x;
    int e0 = row_start[n], e1 = row_start[n + 1];
    int f0 = t, f1 = t + 256;
    float m0 = -INFINITY, d0 = 0.f, q0 = 0.f;
    float m1 = -INFINITY, d1 = 0.f, q1 = 0.f;
    float mi = -INFINITY, di = 0.f, qi = 0.f;
    for (int e = e0; e < e1; ++e) {
        int s = srcs[e];
        const float* xr = x + s * 512;
        float v0 = xr[f0];
        float v1 = xr[f1];
        float vi = (float)s;
        {   float nm = fmaxf(m0, v0), sc = __expf(m0 - nm), ee = __expf(v0 - nm);
            d0 = d0 * sc + ee; q0 = q0 * sc + ee * v0; m0 = nm; }
        {   float nm = fmaxf(m1, v1), sc = __expf(m1 - nm), ee = __expf(v1 - nm);
            d1 = d1 * sc + ee; q1 = q1 * sc + ee * v1; m1 = nm; }
        {   float nm = fmaxf(mi, vi), sc = __expf(mi - nm), ee = __expf(vi - nm);
            di = di * sc + ee; qi = qi * sc + ee * vi; mi = nm; }
    }
    float a0 = q0 / fmaxf(d0, 1e-16f);
    float a1 = q1 / fmaxf(d1, 1e-16f);
    Abuf1[n * 1024 + f0] = f2bf(a0);
    Abuf1[n * 1024 + f1] = f2bf(a1);
    if (t == 0) aggidx[n] = qi / fmaxf(di, 1e-16f);
}

// ---------------- sum aggregation (layer 2) ----------------
// reads h1 (bf16, Abuf2 cols 256..511), writes segsum into Abuf2 cols 0..255
__global__ __launch_bounds__(256) void k_agg2(const int* __restrict__ row_start,
                                              const int* __restrict__ srcs,
                                              unsigned short* __restrict__ Abuf2,
                                              float* __restrict__ sidx) {
    int n = blockIdx.x;
    int t = threadIdx.x;
    int e0 = row_start[n], e1 = row_start[n + 1];
    float acc = 0.f, si = 0.f;
    for (int e = e0; e < e1; ++e) {
        int s = srcs[e];
        acc += bf2f(Abuf2[s * 512 + 256 + t]);
        si += (float)s;
    }
    Abuf2[n * 512 + t] = f2bf(acc);
    if (t == 0) sidx[n] = si;
}

// ---------------- MFMA GEMM: C = A @ Bt^T + rank-1 index terms + bias, leaky ----------------
// A:  [NNODES x KDIM] bf16 row-major.  Bt: [Ncols x KDIM] bf16 row-major (Bt[n][k] = W[k][n])
// epilogue: v = acc + s1[row]*r1[col] + row*r2[col] + bias[col]; leaky(0.01); store
template <int WR, int WC, int WM, int WN, int KDIM, int OSTRIDE, int OOFF, bool OBF16>
__global__ __launch_bounds__(256) void k_gemm(const unsigned short* __restrict__ A,
                                              const unsigned short* __restrict__ Bt,
                                              const float* __restrict__ s1,
                                              const float* __restrict__ r1,
                                              const float* __restrict__ r2,
                                              const float* __restrict__ bias,
                                              void* __restrict__ outp) {
    constexpr int BM = WR * WM * 16;
    constexpr int BN = WC * WN * 16;
    constexpr int BK = 64;
    constexpr int LDSS = BK + 8;  // 72 shorts (144 B, 16B-aligned rows, bank-spread)
    __shared__ __align__(16) unsigned short As[BM * LDSS];
    __shared__ __align__(16) unsigned short Bs[BN * LDSS];

    const int tid = threadIdx.x;
    const int w = tid >> 6;
    const int lane = tid & 63;
    const int lm = lane & 15;
    const int quad = lane >> 4;
    const int wr = w / WC;
    const int wc = w % WC;
    const int rowbase = blockIdx.x * BM;
    const int colbase = blockIdx.y * BN;
    const int wrow = wr * WM * 16;
    const int wcol = wc * WN * 16;

    f32x4 acc[WM][WN];
#pragma unroll
    for (int mi = 0; mi < WM; ++mi)
#pragma unroll
        for (int ni = 0; ni < WN; ++ni) acc[mi][ni] = (f32x4){0.f, 0.f, 0.f, 0.f};

    for (int kt = 0; kt < KDIM; kt += BK) {
        constexpr int CHA = BM * BK / 8;
#pragma unroll
        for (int c = tid; c < CHA; c += 256) {
            int r = c >> 3, off = (c & 7) * 8;
            int gr = rowbase + r;
            if (gr >= NNODES) gr = NNODES - 1;  // clamp: read valid mem, store guarded later
            u32x4 v = *(const u32x4*)(A + gr * KDIM + kt + off);
            *(u32x4*)(As + r * LDSS + off) = v;
        }
        constexpr int CHB = BN * BK / 8;
#pragma unroll
        for (int c = tid; c < CHB; c += 256) {
            int r = c >> 3, off = (c & 7) * 8;
            u32x4 v = *(const u32x4*)(Bt + (colbase + r) * KDIM + kt + off);
            *(u32x4*)(Bs + r * LDSS + off) = v;
        }
        __syncthreads();
#pragma unroll
        for (int kk = 0; kk < BK; kk += 32) {
            bf16x8 af[WM], bfr[WN];
#pragma unroll
            for (int mi = 0; mi < WM; ++mi)
                af[mi] = __builtin_bit_cast(bf16x8,
                    *(const u32x4*)(As + (wrow + mi * 16 + lm) * LDSS + kk + quad * 8));
#pragma unroll
            for (int ni = 0; ni < WN; ++ni)
                bfr[ni] = __builtin_bit_cast(bf16x8,
                    *(const u32x4*)(Bs + (wcol + ni * 16 + lm) * LDSS + kk + quad * 8));
#pragma unroll
            for (int mi = 0; mi < WM; ++mi)
#pragma unroll
                for (int ni = 0; ni < WN; ++ni)
                    acc[mi][ni] = __builtin_amdgcn_mfma_f32_16x16x32_bf16(
                        af[mi], bfr[ni], acc[mi][ni], 0, 0, 0);
        }
        __syncthreads();
    }

#pragma unroll
    for (int ni = 0; ni < WN; ++ni) {
        int gc = colbase + wcol + ni * 16 + lm;
        float r1v = r1[gc], r2v = r2[gc], bv = bias[gc];
#pragma unroll
        for (int mi = 0; mi < WM; ++mi) {
#pragma unroll
            for (int r = 0; r < 4; ++r) {
                int grow = rowbase + wrow + mi * 16 + quad * 4 + r;
                if (grow < NNODES) {
                    float v = acc[mi][ni][r] + s1[grow] * r1v + (float)grow * r2v + bv;
                    v = (v >= 0.f) ? v : 0.01f * v;
                    if (OBF16)
                        ((unsigned short*)outp)[grow * OSTRIDE + OOFF + gc] = f2bf(v);
                    else
                        ((float*)outp)[grow * OSTRIDE + OOFF + gc] = v;
                }
            }
        }
    }
}

// ---------------- head: [h2 | idx] @ Wp/Wr, normalize rotation ----------------
__global__ __launch_bounds__(64) void k_head(const float* __restrict__ h2,
                                             const float* __restrict__ Wp,
                                             const float* __restrict__ bp,
                                             const float* __restrict__ Wr,
                                             const float* __restrict__ br,
                                             float* __restrict__ out) {
    int n = blockIdx.x;
    int l = threadIdx.x;
    float v = h2[n * 64 + l];
    float dots[7];
#pragma unroll
    for (int j = 0; j < 3; ++j) {
        float p = v * Wp[l * 3 + j];
#pragma unroll
        for (int off = 32; off; off >>= 1) p += __shfl_xor(p, off);
        dots[j] = p;
    }
#pragma unroll
    for (int j = 0; j < 4; ++j) {
        float p = v * Wr[l * 4 + j];
#pragma unroll
        for (int off = 32; off; off >>= 1) p += __shfl_xor(p, off);
        dots[3 + j] = p;
    }
    float idx = (float)n;
    float rot[4];
    float nrm = 0.f;
#pragma unroll
    for (int j = 0; j < 4; ++j) {
        rot[j] = dots[3 + j] + idx * Wr[64 * 4 + j] + br[j];
        nrm += rot[j] * rot[j];
    }
    nrm = fmaxf(sqrtf(nrm), 1e-12f);
    if (l < 3)
        out[n * 7 + l] = dots[l] + idx * Wp[64 * 3 + l] + bp[l];
    else if (l < 7)
        out[n * 7 + l] = rot[l - 3] / nrm;
}

extern "C" void kernel_launch(void* const* d_in, const int* in_sizes, int n_in,
                              void* d_out, int out_size, void* d_ws, size_t ws_size,
                              hipStream_t stream) {
    const float* x       = (const float*)d_in[0];
    const float* W1_rel  = (const float*)d_in[1];
    const float* b1      = (const float*)d_in[2];
    const float* W1_root = (const float*)d_in[3];
    const float* W2_rel  = (const float*)d_in[4];
    const float* b2      = (const float*)d_in[5];
    const float* W2_root = (const float*)d_in[6];
    const float* Wp      = (const float*)d_in[7];
    const float* bp      = (const float*)d_in[8];
    const float* Wr      = (const float*)d_in[9];
    const float* br      = (const float*)d_in[10];
    const int*   ei      = (const int*)d_in[11];
    float* out = (float*)d_out;

    // workspace layout (256B aligned)
    char* ws = (char*)d_ws;
    size_t off = 0;
    auto alloc = [&](size_t bytes) {
        size_t o = off;
        off = (off + bytes + 255) & ~(size_t)255;
        return (void*)(ws + o);
    };
    int*   deg       = (int*)alloc(NNODES * 4);
    int*   cursor    = (int*)alloc(NNODES * 4);
    int*   row_start = (int*)alloc((NNODES + 1) * 4);
    int*   srcs      = (int*)alloc(NEDGES * 4);
    float* aggidx    = (float*)alloc(NNODES * 4);
    float* sidx      = (float*)alloc(NNODES * 4);
    unsigned short* Abuf1 = (unsigned short*)alloc((size_t)NNODES * 1024 * 2);
    unsigned short* Abuf2 = (unsigned short*)alloc((size_t)NNODES * 512 * 2);
    unsigned short* Bt1   = (unsigned short*)alloc(256 * 1024 * 2);
    unsigned short* Bt2   = (unsigned short*)alloc(64 * 512 * 2);
    float* h2        = (float*)alloc((size_t)NNODES * 64 * 4);

    hipMemsetAsync(deg, 0, NNODES * 4, stream);

    const int EB = (NEDGES + 255) / 256;  // 782
    k_count<<<EB, 256, 0, stream>>>(ei, deg);
    k_scan<<<1, 1024, 0, stream>>>(deg, row_start, cursor);
    k_scatter<<<EB, 256, 0, stream>>>(ei, cursor, srcs);

    k_bt1<<<(256 * 1024) / 256, 256, 0, stream>>>(W1_rel, W1_root, Bt1);
    k_bt2<<<(64 * 512) / 256, 256, 0, stream>>>(W2_rel, W2_root, Bt2);
    k_xcast<<<(NNODES * 128 + 255) / 256, 256, 0, stream>>>(x, Abuf1);

    k_agg1<<<NNODES, 256, 0, stream>>>(x, row_start, srcs, Abuf1, aggidx);

    // GEMM1: [N x 1024] @ Bt1^T -> h1(bf16) into Abuf2 cols 256..511
    k_gemm<2, 2, 4, 4, 1024, 512, 256, true><<<dim3((NNODES + 127) / 128, 2), 256, 0, stream>>>(
        Abuf1, Bt1, aggidx, W1_rel + 512 * 256, W1_root + 512 * 256, b1, (void*)Abuf2);

    k_agg2<<<NNODES, 256, 0, stream>>>(row_start, srcs, Abuf2, sidx);

    // GEMM2: [N x 512] @ Bt2^T -> h2 (f32)
    k_gemm<4, 1, 2, 4, 512, 64, 0, false><<<dim3((NNODES + 127) / 128, 1), 256, 0, stream>>>(
        Abuf2, Bt2, sidx, W2_rel + 256 * 64, W2_root + 256 * 64, b2, (void*)h2);

    k_head<<<NNODES, 64, 0, stream>>>(h2, Wp, bp, Wr, br, out);
}

// Round 2
// 496.892 us; speedup vs baseline: 1.2405x; 1.2405x over previous
//
#include <hip/hip_runtime.h>

#define NNODES 50000
#define NEDGES 200000
#define NSCANB ((NNODES + 255) / 256)   // 196 scan blocks

typedef short  bf16x8 __attribute__((ext_vector_type(8)));
typedef float  f32x4  __attribute__((ext_vector_type(4)));
typedef unsigned int u32x4 __attribute__((ext_vector_type(4)));

__device__ __forceinline__ unsigned short f2bf(float f) {
    union { float f; unsigned int u; } c; c.f = f;
    unsigned int r = c.u + 0x7fffu + ((c.u >> 16) & 1u);
    return (unsigned short)(r >> 16);
}
__device__ __forceinline__ float bf2f(unsigned short h) {
    union { unsigned int u; float f; } c; c.u = ((unsigned int)h) << 16;
    return c.f;
}

// ---------------- CSR build ----------------
__global__ void k_count(const int* __restrict__ ei, int* __restrict__ deg) {
    int e = blockIdx.x * 256 + threadIdx.x;
    if (e < NEDGES) atomicAdd(&deg[ei[NEDGES + e]], 1);
}

// hierarchical exclusive scan of deg[] -> row_start[]
__global__ __launch_bounds__(256) void k_scanA(const int* __restrict__ deg,
                                               int* __restrict__ rs,
                                               int* __restrict__ partials) {
    __shared__ int sm[256];
    int t = threadIdx.x, i = blockIdx.x * 256 + t;
    int v = (i < NNODES) ? deg[i] : 0;
    sm[t] = v;
    __syncthreads();
#pragma unroll
    for (int off = 1; off < 256; off <<= 1) {
        int u = (t >= off) ? sm[t - off] : 0;
        __syncthreads();
        sm[t] += u;
        __syncthreads();
    }
    if (i < NNODES) rs[i] = sm[t] - v;  // block-local exclusive
    if (t == 255) partials[blockIdx.x] = sm[255];
}

__global__ __launch_bounds__(256) void k_scanB(int* __restrict__ partials) {
    __shared__ int sm[256];
    int t = threadIdx.x;
    int v = (t < NSCANB) ? partials[t] : 0;
    sm[t] = v;
    __syncthreads();
#pragma unroll
    for (int off = 1; off < 256; off <<= 1) {
        int u = (t >= off) ? sm[t - off] : 0;
        __syncthreads();
        sm[t] += u;
        __syncthreads();
    }
    if (t < NSCANB) partials[t] = sm[t] - v;  // exclusive block offsets
}

__global__ __launch_bounds__(256) void k_scanC(int* __restrict__ rs,
                                               const int* __restrict__ partials,
                                               int* __restrict__ cursor) {
    int t = threadIdx.x, b = blockIdx.x, i = b * 256 + t;
    if (i < NNODES) {
        int v = rs[i] + partials[b];
        rs[i] = v;
        cursor[i] = v;
    }
    if (i == 0) rs[NNODES] = NEDGES;
}

__global__ void k_scatter(const int* __restrict__ ei, int* __restrict__ cursor,
                          int* __restrict__ srcs) {
    int e = blockIdx.x * 256 + threadIdx.x;
    if (e < NEDGES) {
        int d = ei[NEDGES + e];
        int p = atomicAdd(&cursor[d], 1);
        srcs[p] = ei[e];
    }
}

// ---------------- weight transposes (bf16) ----------------
__global__ void k_bt1(const float* __restrict__ Wrel, const float* __restrict__ Wroot,
                      unsigned short* __restrict__ Bt) {
    int i = blockIdx.x * 256 + threadIdx.x;
    if (i >= 256 * 1024) return;
    int n = i >> 10, k = i & 1023;
    float v = (k < 512) ? Wrel[k * 256 + n] : Wroot[(k - 512) * 256 + n];
    Bt[i] = f2bf(v);
}
__global__ void k_bt2(const float* __restrict__ Wrel, const float* __restrict__ Wroot,
                      unsigned short* __restrict__ Bt) {
    int i = blockIdx.x * 256 + threadIdx.x;
    if (i >= 64 * 512) return;
    int n = i >> 9, k = i & 511;
    float v = (k < 256) ? Wrel[k * 64 + n] : Wroot[(k - 256) * 64 + n];
    Bt[i] = f2bf(v);
}

// ---------------- softmax aggregation (layer 1), fused x->bf16 cast ----------------
// No max-subtraction: x ~ N(0,1), |x| < ~6, exp() safe in f32. Mathematically
// identical to the ref's max-shifted softmax.
__global__ __launch_bounds__(256) void k_agg1(const float* __restrict__ x,
                                              const int* __restrict__ rs,
                                              const int* __restrict__ srcs,
                                              unsigned short* __restrict__ Abuf1) {
    int n = blockIdx.x;
    int t = threadIdx.x;
    int e0 = rs[n], e1 = rs[n + 1];
    float d0 = 0.f, q0 = 0.f, d1 = 0.f, q1 = 0.f;
    for (int e = e0; e < e1; ++e) {
        int s = srcs[e];
        const float* xr = x + (size_t)s * 512;
        float v0 = xr[t];
        float v1 = xr[t + 256];
        float e0v = __expf(v0);
        float e1v = __expf(v1);
        d0 += e0v; q0 += e0v * v0;
        d1 += e1v; q1 += e1v * v1;
    }
    unsigned short* ab = Abuf1 + (size_t)n * 1024;
    ab[t]       = f2bf(q0 / fmaxf(d0, 1e-16f));
    ab[t + 256] = f2bf(q1 / fmaxf(d1, 1e-16f));
    // fused xcast: cols 512..1023 = bf16(x[n])
    const float* xn = x + (size_t)n * 512;
    ab[t + 512] = f2bf(xn[t]);
    ab[t + 768] = f2bf(xn[t + 256]);
}

// ---------------- per-node index aggregates (softmax over src idx, sum of src idx) ----------------
__global__ __launch_bounds__(256) void k_aggidx(const int* __restrict__ rs,
                                                const int* __restrict__ srcs,
                                                float* __restrict__ aggidx,
                                                float* __restrict__ sidx) {
    int n = blockIdx.x * 256 + threadIdx.x;
    if (n >= NNODES) return;
    int e0 = rs[n], e1 = rs[n + 1];
    float m = -INFINITY, d = 0.f, q = 0.f, si = 0.f;
    for (int e = e0; e < e1; ++e) {
        float v = (float)srcs[e];
        si += v;
        float nm = fmaxf(m, v);
        float sc = __expf(m - nm), ee = __expf(v - nm);
        d = d * sc + ee;
        q = q * sc + ee * v;
        m = nm;
    }
    aggidx[n] = q / fmaxf(d, 1e-16f);
    sidx[n] = si;
}

// ---------------- sum aggregation (layer 2) ----------------
__global__ __launch_bounds__(256) void k_agg2(const int* __restrict__ rs,
                                              const int* __restrict__ srcs,
                                              unsigned short* __restrict__ Abuf2) {
    int n = blockIdx.x;
    int t = threadIdx.x;
    int e0 = rs[n], e1 = rs[n + 1];
    float acc = 0.f;
    for (int e = e0; e < e1; ++e) {
        int s = srcs[e];
        acc += bf2f(Abuf2[(size_t)s * 512 + 256 + t]);
    }
    Abuf2[(size_t)n * 512 + t] = f2bf(acc);
}

// ---------------- MFMA GEMM: C = A @ Bt^T + rank-1 index terms + bias, leaky ----------------
template <int WR, int WC, int WM, int WN, int KDIM, int OSTRIDE, int OOFF, bool OBF16>
__global__ __launch_bounds__(256) void k_gemm(const unsigned short* __restrict__ A,
                                              const unsigned short* __restrict__ Bt,
                                              const float* __restrict__ s1,
                                              const float* __restrict__ r1,
                                              const float* __restrict__ r2,
                                              const float* __restrict__ bias,
                                              void* __restrict__ outp) {
    constexpr int BM = WR * WM * 16;
    constexpr int BN = WC * WN * 16;
    constexpr int BK = 64;
    constexpr int LDSS = BK + 8;
    __shared__ __align__(16) unsigned short As[BM * LDSS];
    __shared__ __align__(16) unsigned short Bs[BN * LDSS];

    const int tid = threadIdx.x;
    const int w = tid >> 6;
    const int lane = tid & 63;
    const int lm = lane & 15;
    const int quad = lane >> 4;
    const int wr = w / WC;
    const int wc = w % WC;
    const int rowbase = blockIdx.x * BM;
    const int colbase = blockIdx.y * BN;
    const int wrow = wr * WM * 16;
    const int wcol = wc * WN * 16;

    f32x4 acc[WM][WN];
#pragma unroll
    for (int mi = 0; mi < WM; ++mi)
#pragma unroll
        for (int ni = 0; ni < WN; ++ni) acc[mi][ni] = (f32x4){0.f, 0.f, 0.f, 0.f};

    for (int kt = 0; kt < KDIM; kt += BK) {
        constexpr int CHA = BM * BK / 8;
#pragma unroll
        for (int c = tid; c < CHA; c += 256) {
            int r = c >> 3, off = (c & 7) * 8;
            int gr = rowbase + r;
            if (gr >= NNODES) gr = NNODES - 1;
            u32x4 v = *(const u32x4*)(A + (size_t)gr * KDIM + kt + off);
            *(u32x4*)(As + r * LDSS + off) = v;
        }
        constexpr int CHB = BN * BK / 8;
#pragma unroll
        for (int c = tid; c < CHB; c += 256) {
            int r = c >> 3, off = (c & 7) * 8;
            u32x4 v = *(const u32x4*)(Bt + (size_t)(colbase + r) * KDIM + kt + off);
            *(u32x4*)(Bs + r * LDSS + off) = v;
        }
        __syncthreads();
#pragma unroll
        for (int kk = 0; kk < BK; kk += 32) {
            bf16x8 af[WM], bfr[WN];
#pragma unroll
            for (int mi = 0; mi < WM; ++mi)
                af[mi] = __builtin_bit_cast(bf16x8,
                    *(const u32x4*)(As + (wrow + mi * 16 + lm) * LDSS + kk + quad * 8));
#pragma unroll
            for (int ni = 0; ni < WN; ++ni)
                bfr[ni] = __builtin_bit_cast(bf16x8,
                    *(const u32x4*)(Bs + (wcol + ni * 16 + lm) * LDSS + kk + quad * 8));
#pragma unroll
            for (int mi = 0; mi < WM; ++mi)
#pragma unroll
                for (int ni = 0; ni < WN; ++ni)
                    acc[mi][ni] = __builtin_amdgcn_mfma_f32_16x16x32_bf16(
                        af[mi], bfr[ni], acc[mi][ni], 0, 0, 0);
        }
        __syncthreads();
    }

#pragma unroll
    for (int ni = 0; ni < WN; ++ni) {
        int gc = colbase + wcol + ni * 16 + lm;
        float r1v = r1[gc], r2v = r2[gc], bv = bias[gc];
#pragma unroll
        for (int mi = 0; mi < WM; ++mi) {
#pragma unroll
            for (int r = 0; r < 4; ++r) {
                int grow = rowbase + wrow + mi * 16 + quad * 4 + r;
                if (grow < NNODES) {
                    float v = acc[mi][ni][r] + s1[grow] * r1v + (float)grow * r2v + bv;
                    v = (v >= 0.f) ? v : 0.01f * v;
                    if (OBF16)
                        ((unsigned short*)outp)[(size_t)grow * OSTRIDE + OOFF + gc] = f2bf(v);
                    else
                        ((float*)outp)[(size_t)grow * OSTRIDE + OOFF + gc] = v;
                }
            }
        }
    }
}

// ---------------- head: [h2 | idx] @ Wp/Wr, normalize rotation ----------------
__global__ __launch_bounds__(64) void k_head(const float* __restrict__ h2,
                                             const float* __restrict__ Wp,
                                             const float* __restrict__ bp,
                                             const float* __restrict__ Wr,
                                             const float* __restrict__ br,
                                             float* __restrict__ out) {
    int n = blockIdx.x;
    int l = threadIdx.x;
    float v = h2[(size_t)n * 64 + l];
    float dots[7];
#pragma unroll
    for (int j = 0; j < 3; ++j) {
        float p = v * Wp[l * 3 + j];
#pragma unroll
        for (int off = 32; off; off >>= 1) p += __shfl_xor(p, off);
        dots[j] = p;
    }
#pragma unroll
    for (int j = 0; j < 4; ++j) {
        float p = v * Wr[l * 4 + j];
#pragma unroll
        for (int off = 32; off; off >>= 1) p += __shfl_xor(p, off);
        dots[3 + j] = p;
    }
    float idx = (float)n;
    float rot[4];
    float nrm = 0.f;
#pragma unroll
    for (int j = 0; j < 4; ++j) {
        rot[j] = dots[3 + j] + idx * Wr[64 * 4 + j] + br[j];
        nrm += rot[j] * rot[j];
    }
    nrm = fmaxf(sqrtf(nrm), 1e-12f);
    if (l < 3)
        out[n * 7 + l] = dots[l] + idx * Wp[64 * 3 + l] + bp[l];
    else if (l < 7)
        out[n * 7 + l] = rot[l - 3] / nrm;
}

extern "C" void kernel_launch(void* const* d_in, const int* in_sizes, int n_in,
                              void* d_out, int out_size, void* d_ws, size_t ws_size,
                              hipStream_t stream) {
    const float* x       = (const float*)d_in[0];
    const float* W1_rel  = (const float*)d_in[1];
    const float* b1      = (const float*)d_in[2];
    const float* W1_root = (const float*)d_in[3];
    const float* W2_rel  = (const float*)d_in[4];
    const float* b2      = (const float*)d_in[5];
    const float* W2_root = (const float*)d_in[6];
    const float* Wp      = (const float*)d_in[7];
    const float* bp      = (const float*)d_in[8];
    const float* Wr      = (const float*)d_in[9];
    const float* br      = (const float*)d_in[10];
    const int*   ei      = (const int*)d_in[11];
    float* out = (float*)d_out;

    char* ws = (char*)d_ws;
    size_t off = 0;
    auto alloc = [&](size_t bytes) {
        size_t o = off;
        off = (off + bytes + 255) & ~(size_t)255;
        return (void*)(ws + o);
    };
    int*   deg       = (int*)alloc(NNODES * 4);
    int*   cursor    = (int*)alloc(NNODES * 4);
    int*   row_start = (int*)alloc((NNODES + 1) * 4);
    int*   srcs      = (int*)alloc(NEDGES * 4);
    int*   partials  = (int*)alloc(NSCANB * 4);
    float* aggidx    = (float*)alloc(NNODES * 4);
    float* sidx      = (float*)alloc(NNODES * 4);
    unsigned short* Abuf1 = (unsigned short*)alloc((size_t)NNODES * 1024 * 2);
    unsigned short* Abuf2 = (unsigned short*)alloc((size_t)NNODES * 512 * 2);
    unsigned short* Bt1   = (unsigned short*)alloc(256 * 1024 * 2);
    unsigned short* Bt2   = (unsigned short*)alloc(64 * 512 * 2);
    float* h2        = (float*)alloc((size_t)NNODES * 64 * 4);

    hipMemsetAsync(deg, 0, NNODES * 4, stream);

    const int EB = (NEDGES + 255) / 256;
    k_count<<<EB, 256, 0, stream>>>(ei, deg);
    k_scanA<<<NSCANB, 256, 0, stream>>>(deg, row_start, partials);
    k_scanB<<<1, 256, 0, stream>>>(partials);
    k_scanC<<<NSCANB, 256, 0, stream>>>(row_start, partials, cursor);
    k_scatter<<<EB, 256, 0, stream>>>(ei, cursor, srcs);

    k_bt1<<<(256 * 1024) / 256, 256, 0, stream>>>(W1_rel, W1_root, Bt1);
    k_bt2<<<(64 * 512) / 256, 256, 0, stream>>>(W2_rel, W2_root, Bt2);

    k_agg1<<<NNODES, 256, 0, stream>>>(x, row_start, srcs, Abuf1);
    k_aggidx<<<NSCANB, 256, 0, stream>>>(row_start, srcs, aggidx, sidx);

    // GEMM1: [N x 1024] @ Bt1^T -> h1(bf16) into Abuf2 cols 256..511
    k_gemm<2, 2, 4, 4, 1024, 512, 256, true><<<dim3((NNODES + 127) / 128, 2), 256, 0, stream>>>(
        Abuf1, Bt1, aggidx, W1_rel + 512 * 256, W1_root + 512 * 256, b1, (void*)Abuf2);

    k_agg2<<<NNODES, 256, 0, stream>>>(row_start, srcs, Abuf2);

    // GEMM2: [N x 512] @ Bt2^T -> h2 (f32)
    k_gemm<4, 1, 2, 4, 512, 64, 0, false><<<dim3((NNODES + 127) / 128, 1), 256, 0, stream>>>(
        Abuf2, Bt2, sidx, W2_rel + 256 * 64, W2_root + 256 * 64, b2, (void*)h2);

    k_head<<<NNODES, 64, 0, stream>>>(h2, Wp, bp, Wr, br, out);
}

// Round 3
// 436.741 us; speedup vs baseline: 1.4114x; 1.1377x over previous
//
#include <hip/hip_runtime.h>

#define NNODES 50000
#define NEDGES 200000
#define NSCANB ((NNODES + 255) / 256)   // 196 scan blocks

typedef short  bf16x8 __attribute__((ext_vector_type(8)));
typedef float  f32x4  __attribute__((ext_vector_type(4)));
typedef unsigned int u32x4 __attribute__((ext_vector_type(4)));

__device__ __forceinline__ unsigned short f2bf(float f) {
    union { float f; unsigned int u; } c; c.f = f;
    unsigned int r = c.u + 0x7fffu + ((c.u >> 16) & 1u);
    return (unsigned short)(r >> 16);
}
__device__ __forceinline__ float bf2f(unsigned short h) {
    union { unsigned int u; float f; } c; c.u = ((unsigned int)h) << 16;
    return c.f;
}

// ---------------- CSR build ----------------
__global__ void k_count(const int* __restrict__ ei, int* __restrict__ deg) {
    int e = blockIdx.x * 256 + threadIdx.x;
    if (e < NEDGES) atomicAdd(&deg[ei[NEDGES + e]], 1);
}

__global__ __launch_bounds__(256) void k_scanA(const int* __restrict__ deg,
                                               int* __restrict__ rs,
                                               int* __restrict__ partials) {
    __shared__ int sm[256];
    int t = threadIdx.x, i = blockIdx.x * 256 + t;
    int v = (i < NNODES) ? deg[i] : 0;
    sm[t] = v;
    __syncthreads();
#pragma unroll
    for (int off = 1; off < 256; off <<= 1) {
        int u = (t >= off) ? sm[t - off] : 0;
        __syncthreads();
        sm[t] += u;
        __syncthreads();
    }
    if (i < NNODES) rs[i] = sm[t] - v;
    if (t == 255) partials[blockIdx.x] = sm[255];
}

__global__ __launch_bounds__(256) void k_scanB(int* __restrict__ partials) {
    __shared__ int sm[256];
    int t = threadIdx.x;
    int v = (t < NSCANB) ? partials[t] : 0;
    sm[t] = v;
    __syncthreads();
#pragma unroll
    for (int off = 1; off < 256; off <<= 1) {
        int u = (t >= off) ? sm[t - off] : 0;
        __syncthreads();
        sm[t] += u;
        __syncthreads();
    }
    if (t < NSCANB) partials[t] = sm[t] - v;
}

__global__ __launch_bounds__(256) void k_scanC(int* __restrict__ rs,
                                               const int* __restrict__ partials,
                                               int* __restrict__ cursor) {
    int t = threadIdx.x, b = blockIdx.x, i = b * 256 + t;
    if (i < NNODES) {
        int v = rs[i] + partials[b];
        rs[i] = v;
        cursor[i] = v;
    }
    if (i == 0) rs[NNODES] = NEDGES;
}

__global__ void k_scatter(const int* __restrict__ ei, int* __restrict__ cursor,
                          int* __restrict__ srcs) {
    int e = blockIdx.x * 256 + threadIdx.x;
    if (e < NEDGES) {
        int d = ei[NEDGES + e];
        int p = atomicAdd(&cursor[d], 1);
        srcs[p] = ei[e];
    }
}

// ---------------- weight transposes (bf16) ----------------
__global__ void k_bt1(const float* __restrict__ Wrel, const float* __restrict__ Wroot,
                      unsigned short* __restrict__ Bt) {
    int i = blockIdx.x * 256 + threadIdx.x;
    if (i >= 256 * 1024) return;
    int n = i >> 10, k = i & 1023;
    float v = (k < 512) ? Wrel[k * 256 + n] : Wroot[(k - 512) * 256 + n];
    Bt[i] = f2bf(v);
}
__global__ void k_bt2(const float* __restrict__ Wrel, const float* __restrict__ Wroot,
                      unsigned short* __restrict__ Bt) {
    int i = blockIdx.x * 256 + threadIdx.x;
    if (i >= 64 * 512) return;
    int n = i >> 9, k = i & 511;
    float v = (k < 256) ? Wrel[k * 64 + n] : Wroot[(k - 256) * 64 + n];
    Bt[i] = f2bf(v);
}

// ---------------- softmax aggregation (layer 1), fused x->bf16 cast ----------------
__global__ __launch_bounds__(256) void k_agg1(const float* __restrict__ x,
                                              const int* __restrict__ rs,
                                              const int* __restrict__ srcs,
                                              unsigned short* __restrict__ Abuf1) {
    int n = blockIdx.x;
    int t = threadIdx.x;
    int e0 = rs[n], e1 = rs[n + 1];
    float d0 = 0.f, q0 = 0.f, d1 = 0.f, q1 = 0.f;
    for (int e = e0; e < e1; ++e) {
        int s = srcs[e];
        const float* xr = x + (size_t)s * 512;
        float v0 = xr[t];
        float v1 = xr[t + 256];
        float e0v = __expf(v0);
        float e1v = __expf(v1);
        d0 += e0v; q0 += e0v * v0;
        d1 += e1v; q1 += e1v * v1;
    }
    unsigned short* ab = Abuf1 + (size_t)n * 1024;
    ab[t]       = f2bf(q0 / fmaxf(d0, 1e-16f));
    ab[t + 256] = f2bf(q1 / fmaxf(d1, 1e-16f));
    const float* xn = x + (size_t)n * 512;
    ab[t + 512] = f2bf(xn[t]);
    ab[t + 768] = f2bf(xn[t + 256]);
}

// ---------------- per-node index aggregates ----------------
__global__ __launch_bounds__(256) void k_aggidx(const int* __restrict__ rs,
                                                const int* __restrict__ srcs,
                                                float* __restrict__ aggidx,
                                                float* __restrict__ sidx) {
    int n = blockIdx.x * 256 + threadIdx.x;
    if (n >= NNODES) return;
    int e0 = rs[n], e1 = rs[n + 1];
    float m = -INFINITY, d = 0.f, q = 0.f, si = 0.f;
    for (int e = e0; e < e1; ++e) {
        float v = (float)srcs[e];
        si += v;
        float nm = fmaxf(m, v);
        float sc = __expf(m - nm), ee = __expf(v - nm);
        d = d * sc + ee;
        q = q * sc + ee * v;
        m = nm;
    }
    aggidx[n] = q / fmaxf(d, 1e-16f);
    sidx[n] = si;
}

// ---------------- sum aggregation (layer 2) ----------------
__global__ __launch_bounds__(256) void k_agg2(const int* __restrict__ rs,
                                              const int* __restrict__ srcs,
                                              unsigned short* __restrict__ Abuf2) {
    int n = blockIdx.x;
    int t = threadIdx.x;
    int e0 = rs[n], e1 = rs[n + 1];
    float acc = 0.f;
    for (int e = e0; e < e1; ++e) {
        int s = srcs[e];
        acc += bf2f(Abuf2[(size_t)s * 512 + 256 + t]);
    }
    Abuf2[(size_t)n * 512 + t] = f2bf(acc);
}

// ---------------- MFMA GEMM with global_load_lds staging + XOR-swizzled LDS ----------------
// A: [NNODES x KDIM] bf16 row-major. Bt: [Ncols x KDIM] bf16 row-major.
// LDS layout: row stride 64 shorts (unpadded, DMA-compatible); 16B chunk c of
// row r stored at physical chunk c ^ (r&7)  -> b128 frag reads spread over all
// 32 banks with only free 2-way aliasing.
// epilogue: v = acc + s1[row]*r1[col] + row*r2[col] + bias[col]; leaky(0.01)
template <int WR, int WC, int WM, int WN, int KDIM, int OSTRIDE, int OOFF, bool OBF16>
__global__ __launch_bounds__(256) void k_gemm(const unsigned short* __restrict__ A,
                                              const unsigned short* __restrict__ Bt,
                                              const float* __restrict__ s1,
                                              const float* __restrict__ r1,
                                              const float* __restrict__ r2,
                                              const float* __restrict__ bias,
                                              void* __restrict__ outp) {
    constexpr int BM = WR * WM * 16;
    constexpr int BN = WC * WN * 16;
    constexpr int BK = 64;   // shorts per row in LDS
    __shared__ __align__(16) unsigned short As[BM * BK];
    __shared__ __align__(16) unsigned short Bs[BN * BK];

    const int tid = threadIdx.x;
    const int w = tid >> 6;
    const int lane = tid & 63;
    const int lm = lane & 15;
    const int quad = lane >> 4;
    const int wr = w / WC;
    const int wc = w % WC;
    const int rowbase = blockIdx.x * BM;
    const int colbase = blockIdx.y * BN;
    const int wrow = wr * WM * 16;
    const int wcol = wc * WN * 16;

    // staging geometry: each global_load_lds covers 64 lanes x 16B = 8 rows
    const int rsub = lane >> 3;           // row within an 8-row segment
    const int csw = (lane & 7) ^ rsub;    // swizzled SOURCE chunk for this lane

    f32x4 acc[WM][WN];
#pragma unroll
    for (int mi = 0; mi < WM; ++mi)
#pragma unroll
        for (int ni = 0; ni < WN; ++ni) acc[mi][ni] = (f32x4){0.f, 0.f, 0.f, 0.f};

    for (int kt = 0; kt < KDIM; kt += BK) {
#pragma unroll
        for (int l = 0; l < BM / 32; ++l) {
            int r = w * (BM / 4) + l * 8;                  // wave-uniform segment base row
            int gr = rowbase + r + rsub;
            if (gr >= NNODES) gr = NNODES - 1;
            const unsigned short* gp = A + (size_t)gr * KDIM + kt + csw * 8;
            __builtin_amdgcn_global_load_lds(
                (const __attribute__((address_space(1))) void*)gp,
                (__attribute__((address_space(3))) void*)(As + r * BK), 16, 0, 0);
        }
#pragma unroll
        for (int l = 0; l < BN / 32; ++l) {
            int r = w * (BN / 4) + l * 8;
            const unsigned short* gp = Bt + (size_t)(colbase + r + rsub) * KDIM + kt + csw * 8;
            __builtin_amdgcn_global_load_lds(
                (const __attribute__((address_space(1))) void*)gp,
                (__attribute__((address_space(3))) void*)(Bs + r * BK), 16, 0, 0);
        }
        __syncthreads();
#pragma unroll
        for (int kk = 0; kk < BK; kk += 32) {
            const int kidx = (kk >> 3) + quad;             // logical chunk 0..7
            const int phys = kidx ^ (lm & 7);              // swizzled chunk
            bf16x8 af[WM], bfr[WN];
#pragma unroll
            for (int mi = 0; mi < WM; ++mi)
                af[mi] = __builtin_bit_cast(bf16x8,
                    *(const u32x4*)(As + (wrow + mi * 16 + lm) * BK + phys * 8));
#pragma unroll
            for (int ni = 0; ni < WN; ++ni)
                bfr[ni] = __builtin_bit_cast(bf16x8,
                    *(const u32x4*)(Bs + (wcol + ni * 16 + lm) * BK + phys * 8));
#pragma unroll
            for (int mi = 0; mi < WM; ++mi)
#pragma unroll
                for (int ni = 0; ni < WN; ++ni)
                    acc[mi][ni] = __builtin_amdgcn_mfma_f32_16x16x32_bf16(
                        af[mi], bfr[ni], acc[mi][ni], 0, 0, 0);
        }
        __syncthreads();
    }

#pragma unroll
    for (int ni = 0; ni < WN; ++ni) {
        int gc = colbase + wcol + ni * 16 + lm;
        float r1v = r1[gc], r2v = r2[gc], bv = bias[gc];
#pragma unroll
        for (int mi = 0; mi < WM; ++mi) {
#pragma unroll
            for (int r = 0; r < 4; ++r) {
                int grow = rowbase + wrow + mi * 16 + quad * 4 + r;
                if (grow < NNODES) {
                    float v = acc[mi][ni][r] + s1[grow] * r1v + (float)grow * r2v + bv;
                    v = (v >= 0.f) ? v : 0.01f * v;
                    if (OBF16)
                        ((unsigned short*)outp)[(size_t)grow * OSTRIDE + OOFF + gc] = f2bf(v);
                    else
                        ((float*)outp)[(size_t)grow * OSTRIDE + OOFF + gc] = v;
                }
            }
        }
    }
}

// ---------------- head ----------------
__global__ __launch_bounds__(64) void k_head(const float* __restrict__ h2,
                                             const float* __restrict__ Wp,
                                             const float* __restrict__ bp,
                                             const float* __restrict__ Wr,
                                             const float* __restrict__ br,
                                             float* __restrict__ out) {
    int n = blockIdx.x;
    int l = threadIdx.x;
    float v = h2[(size_t)n * 64 + l];
    float dots[7];
#pragma unroll
    for (int j = 0; j < 3; ++j) {
        float p = v * Wp[l * 3 + j];
#pragma unroll
        for (int off = 32; off; off >>= 1) p += __shfl_xor(p, off);
        dots[j] = p;
    }
#pragma unroll
    for (int j = 0; j < 4; ++j) {
        float p = v * Wr[l * 4 + j];
#pragma unroll
        for (int off = 32; off; off >>= 1) p += __shfl_xor(p, off);
        dots[3 + j] = p;
    }
    float idx = (float)n;
    float rot[4];
    float nrm = 0.f;
#pragma unroll
    for (int j = 0; j < 4; ++j) {
        rot[j] = dots[3 + j] + idx * Wr[64 * 4 + j] + br[j];
        nrm += rot[j] * rot[j];
    }
    nrm = fmaxf(sqrtf(nrm), 1e-12f);
    if (l < 3)
        out[n * 7 + l] = dots[l] + idx * Wp[64 * 3 + l] + bp[l];
    else if (l < 7)
        out[n * 7 + l] = rot[l - 3] / nrm;
}

extern "C" void kernel_launch(void* const* d_in, const int* in_sizes, int n_in,
                              void* d_out, int out_size, void* d_ws, size_t ws_size,
                              hipStream_t stream) {
    const float* x       = (const float*)d_in[0];
    const float* W1_rel  = (const float*)d_in[1];
    const float* b1      = (const float*)d_in[2];
    const float* W1_root = (const float*)d_in[3];
    const float* W2_rel  = (const float*)d_in[4];
    const float* b2      = (const float*)d_in[5];
    const float* W2_root = (const float*)d_in[6];
    const float* Wp      = (const float*)d_in[7];
    const float* bp      = (const float*)d_in[8];
    const float* Wr      = (const float*)d_in[9];
    const float* br      = (const float*)d_in[10];
    const int*   ei      = (const int*)d_in[11];
    float* out = (float*)d_out;

    char* ws = (char*)d_ws;
    size_t off = 0;
    auto alloc = [&](size_t bytes) {
        size_t o = off;
        off = (off + bytes + 255) & ~(size_t)255;
        return (void*)(ws + o);
    };
    int*   deg       = (int*)alloc(NNODES * 4);
    int*   cursor    = (int*)alloc(NNODES * 4);
    int*   row_start = (int*)alloc((NNODES + 1) * 4);
    int*   srcs      = (int*)alloc(NEDGES * 4);
    int*   partials  = (int*)alloc(NSCANB * 4);
    float* aggidx    = (float*)alloc(NNODES * 4);
    float* sidx      = (float*)alloc(NNODES * 4);
    unsigned short* Abuf1 = (unsigned short*)alloc((size_t)NNODES * 1024 * 2);
    unsigned short* Abuf2 = (unsigned short*)alloc((size_t)NNODES * 512 * 2);
    unsigned short* Bt1   = (unsigned short*)alloc(256 * 1024 * 2);
    unsigned short* Bt2   = (unsigned short*)alloc(64 * 512 * 2);
    float* h2        = (float*)alloc((size_t)NNODES * 64 * 4);

    hipMemsetAsync(deg, 0, NNODES * 4, stream);

    const int EB = (NEDGES + 255) / 256;
    k_count<<<EB, 256, 0, stream>>>(ei, deg);
    k_scanA<<<NSCANB, 256, 0, stream>>>(deg, row_start, partials);
    k_scanB<<<1, 256, 0, stream>>>(partials);
    k_scanC<<<NSCANB, 256, 0, stream>>>(row_start, partials, cursor);
    k_scatter<<<EB, 256, 0, stream>>>(ei, cursor, srcs);

    k_bt1<<<(256 * 1024) / 256, 256, 0, stream>>>(W1_rel, W1_root, Bt1);
    k_bt2<<<(64 * 512) / 256, 256, 0, stream>>>(W2_rel, W2_root, Bt2);

    k_agg1<<<NNODES, 256, 0, stream>>>(x, row_start, srcs, Abuf1);
    k_aggidx<<<NSCANB, 256, 0, stream>>>(row_start, srcs, aggidx, sidx);

    // GEMM1: [N x 1024] @ Bt1^T -> h1(bf16) into Abuf2 cols 256..511
    k_gemm<2, 2, 4, 4, 1024, 512, 256, true><<<dim3((NNODES + 127) / 128, 2), 256, 0, stream>>>(
        Abuf1, Bt1, aggidx, W1_rel + 512 * 256, W1_root + 512 * 256, b1, (void*)Abuf2);

    k_agg2<<<NNODES, 256, 0, stream>>>(row_start, srcs, Abuf2);

    // GEMM2: [N x 512] @ Bt2^T -> h2 (f32)
    k_gemm<4, 1, 2, 4, 512, 64, 0, false><<<dim3((NNODES + 127) / 128, 1), 256, 0, stream>>>(
        Abuf2, Bt2, sidx, W2_rel + 256 * 64, W2_root + 256 * 64, b2, (void*)h2);

    k_head<<<NNODES, 64, 0, stream>>>(h2, Wp, bp, Wr, br, out);
}

// Round 4
// 435.843 us; speedup vs baseline: 1.4143x; 1.0021x over previous
//
#include <hip/hip_runtime.h>

#define NNODES 50000
#define NEDGES 200000
#define NSCANB ((NNODES + 255) / 256)   // 196 scan blocks

typedef short  bf16x8 __attribute__((ext_vector_type(8)));
typedef float  f32x4  __attribute__((ext_vector_type(4)));
typedef unsigned int u32x4 __attribute__((ext_vector_type(4)));

__device__ __forceinline__ unsigned short f2bf(float f) {
    union { float f; unsigned int u; } c; c.f = f;
    unsigned int r = c.u + 0x7fffu + ((c.u >> 16) & 1u);
    return (unsigned short)(r >> 16);
}
__device__ __forceinline__ float bf2f(unsigned short h) {
    union { unsigned int u; float f; } c; c.u = ((unsigned int)h) << 16;
    return c.f;
}

// ---------------- CSR build ----------------
__global__ void k_count(const int* __restrict__ ei, int* __restrict__ deg) {
    int e = blockIdx.x * 256 + threadIdx.x;
    if (e < NEDGES) atomicAdd(&deg[ei[NEDGES + e]], 1);
}

__global__ __launch_bounds__(256) void k_scanA(const int* __restrict__ deg,
                                               int* __restrict__ rs,
                                               int* __restrict__ partials) {
    __shared__ int sm[256];
    int t = threadIdx.x, i = blockIdx.x * 256 + t;
    int v = (i < NNODES) ? deg[i] : 0;
    sm[t] = v;
    __syncthreads();
#pragma unroll
    for (int off = 1; off < 256; off <<= 1) {
        int u = (t >= off) ? sm[t - off] : 0;
        __syncthreads();
        sm[t] += u;
        __syncthreads();
    }
    if (i < NNODES) rs[i] = sm[t] - v;
    if (t == 255) partials[blockIdx.x] = sm[255];
}

__global__ __launch_bounds__(256) void k_scanB(int* __restrict__ partials) {
    __shared__ int sm[256];
    int t = threadIdx.x;
    int v = (t < NSCANB) ? partials[t] : 0;
    sm[t] = v;
    __syncthreads();
#pragma unroll
    for (int off = 1; off < 256; off <<= 1) {
        int u = (t >= off) ? sm[t - off] : 0;
        __syncthreads();
        sm[t] += u;
        __syncthreads();
    }
    if (t < NSCANB) partials[t] = sm[t] - v;
}

__global__ __launch_bounds__(256) void k_scanC(int* __restrict__ rs,
                                               const int* __restrict__ partials,
                                               int* __restrict__ cursor) {
    int t = threadIdx.x, b = blockIdx.x, i = b * 256 + t;
    if (i < NNODES) {
        int v = rs[i] + partials[b];
        rs[i] = v;
        cursor[i] = v;
    }
    if (i == 0) rs[NNODES] = NEDGES;
}

__global__ void k_scatter(const int* __restrict__ ei, int* __restrict__ cursor,
                          int* __restrict__ srcs) {
    int e = blockIdx.x * 256 + threadIdx.x;
    if (e < NEDGES) {
        int d = ei[NEDGES + e];
        int p = atomicAdd(&cursor[d], 1);
        srcs[p] = ei[e];
    }
}

// ---------------- weight transposes (bf16) ----------------
__global__ void k_bt1(const float* __restrict__ Wrel, const float* __restrict__ Wroot,
                      unsigned short* __restrict__ Bt) {
    int i = blockIdx.x * 256 + threadIdx.x;
    if (i >= 256 * 1024) return;
    int n = i >> 10, k = i & 1023;
    float v = (k < 512) ? Wrel[k * 256 + n] : Wroot[(k - 512) * 256 + n];
    Bt[i] = f2bf(v);
}
__global__ void k_bt2(const float* __restrict__ Wrel, const float* __restrict__ Wroot,
                      unsigned short* __restrict__ Bt) {
    int i = blockIdx.x * 256 + threadIdx.x;
    if (i >= 64 * 512) return;
    int n = i >> 9, k = i & 511;
    float v = (k < 256) ? Wrel[k * 64 + n] : Wroot[(k - 256) * 64 + n];
    Bt[i] = f2bf(v);
}

// ---------------- x -> bf16 copy (xb), 8 elems/thread ----------------
__global__ __launch_bounds__(256) void k_xcastb(const float* __restrict__ x,
                                                unsigned short* __restrict__ xb) {
    int i = blockIdx.x * 256 + threadIdx.x;   // over NNODES*64
    int n = i >> 6, c8 = (i & 63) * 8;
    const float* xp = x + (size_t)n * 512 + c8;
    float4 a = *(const float4*)xp;
    float4 b = *(const float4*)(xp + 4);
    unsigned short o[8];
    o[0] = f2bf(a.x); o[1] = f2bf(a.y); o[2] = f2bf(a.z); o[3] = f2bf(a.w);
    o[4] = f2bf(b.x); o[5] = f2bf(b.y); o[6] = f2bf(b.z); o[7] = f2bf(b.w);
    *(u32x4*)(xb + (size_t)n * 512 + c8) = *(const u32x4*)o;
}

// ---------------- softmax aggregation (layer 1) over bf16 x ----------------
// block = one dst node; thread t handles cols 2t, 2t+1 (one uint load/edge).
// No max-subtraction: |x| < ~6, exp() safe in f32.
__global__ __launch_bounds__(256) void k_agg1(const unsigned short* __restrict__ xb,
                                              const int* __restrict__ rs,
                                              const int* __restrict__ srcs,
                                              unsigned short* __restrict__ AggBuf) {
    int n = blockIdx.x;
    int t = threadIdx.x;
    int e0 = rs[n], e1 = rs[n + 1];
    float d0 = 0.f, q0 = 0.f, d1 = 0.f, q1 = 0.f;
    for (int e = e0; e < e1; ++e) {
        int s = srcs[e];
        unsigned int v = *(const unsigned int*)(xb + (size_t)s * 512 + t * 2);
        float v0 = bf2f((unsigned short)(v & 0xffffu));
        float v1 = bf2f((unsigned short)(v >> 16));
        float e0v = __expf(v0);
        float e1v = __expf(v1);
        d0 += e0v; q0 += e0v * v0;
        d1 += e1v; q1 += e1v * v1;
    }
    float a0 = q0 / fmaxf(d0, 1e-16f);
    float a1 = q1 / fmaxf(d1, 1e-16f);
    unsigned int o = (unsigned int)f2bf(a0) | ((unsigned int)f2bf(a1) << 16);
    *(unsigned int*)(AggBuf + (size_t)n * 512 + t * 2) = o;
}

// ---------------- per-node index aggregates ----------------
__global__ __launch_bounds__(256) void k_aggidx(const int* __restrict__ rs,
                                                const int* __restrict__ srcs,
                                                float* __restrict__ aggidx,
                                                float* __restrict__ sidx) {
    int n = blockIdx.x * 256 + threadIdx.x;
    if (n >= NNODES) return;
    int e0 = rs[n], e1 = rs[n + 1];
    float m = -INFINITY, d = 0.f, q = 0.f, si = 0.f;
    for (int e = e0; e < e1; ++e) {
        float v = (float)srcs[e];
        si += v;
        float nm = fmaxf(m, v);
        float sc = __expf(m - nm), ee = __expf(v - nm);
        d = d * sc + ee;
        q = q * sc + ee * v;
        m = nm;
    }
    aggidx[n] = q / fmaxf(d, 1e-16f);
    sidx[n] = si;
}

// ---------------- sum aggregation (layer 2): 2 nodes per block ----------------
// gathers contiguous 512B rows of H1 (256 bf16), writes SegBuf rows.
__global__ __launch_bounds__(256) void k_agg2(const int* __restrict__ rs,
                                              const int* __restrict__ srcs,
                                              const unsigned short* __restrict__ H1,
                                              unsigned short* __restrict__ Seg) {
    int half = threadIdx.x >> 7;
    int t = threadIdx.x & 127;      // handles cols 2t, 2t+1
    int n = blockIdx.x * 2 + half;  // NNODES even
    int e0 = rs[n], e1 = rs[n + 1];
    float a0 = 0.f, a1 = 0.f;
    for (int e = e0; e < e1; ++e) {
        int s = srcs[e];
        unsigned int v = *(const unsigned int*)(H1 + (size_t)s * 256 + t * 2);
        a0 += bf2f((unsigned short)(v & 0xffffu));
        a1 += bf2f((unsigned short)(v >> 16));
    }
    unsigned int o = (unsigned int)f2bf(a0) | ((unsigned int)f2bf(a1) << 16);
    *(unsigned int*)(Seg + (size_t)n * 256 + t * 2) = o;
}

// ---------------- MFMA GEMM, split-A staging + global_load_lds + XOR swizzle ----
// A-tile k<KS comes from A1 (row stride S1), k>=KS from A2 (row stride S2).
// Bt: [Ncols x KDIM] bf16 row-major (Bt[n][k] = W[k][n]).
// LDS: row stride 64 shorts, 16B chunk c of row r at physical chunk c^(r&7).
// epilogue: v = acc + s1[row]*r1[col] + row*r2[col] + bias[col]; leaky(0.01)
template <int WR, int WC, int WM, int WN, int KS, int KDIM, int S1, int S2,
          int OSTRIDE, bool OBF16>
__global__ __launch_bounds__(256) void k_gemm(const unsigned short* __restrict__ A1,
                                              const unsigned short* __restrict__ A2,
                                              const unsigned short* __restrict__ Bt,
                                              const float* __restrict__ s1,
                                              const float* __restrict__ r1,
                                              const float* __restrict__ r2,
                                              const float* __restrict__ bias,
                                              void* __restrict__ outp) {
    constexpr int BM = WR * WM * 16;
    constexpr int BN = WC * WN * 16;
    constexpr int BK = 64;
    __shared__ __align__(16) unsigned short As[BM * BK];
    __shared__ __align__(16) unsigned short Bs[BN * BK];

    const int tid = threadIdx.x;
    const int w = tid >> 6;
    const int lane = tid & 63;
    const int lm = lane & 15;
    const int quad = lane >> 4;
    const int wr = w / WC;
    const int wc = w % WC;
    const int rowbase = blockIdx.x * BM;
    const int colbase = blockIdx.y * BN;
    const int wrow = wr * WM * 16;
    const int wcol = wc * WN * 16;

    const int rsub = lane >> 3;
    const int csw = (lane & 7) ^ rsub;

    f32x4 acc[WM][WN];
#pragma unroll
    for (int mi = 0; mi < WM; ++mi)
#pragma unroll
        for (int ni = 0; ni < WN; ++ni) acc[mi][ni] = (f32x4){0.f, 0.f, 0.f, 0.f};

    for (int kt = 0; kt < KDIM; kt += BK) {
        const unsigned short* Ab;
        int Astr, kof;
        if (kt < KS) { Ab = A1; Astr = S1; kof = kt; }
        else         { Ab = A2; Astr = S2; kof = kt - KS; }
#pragma unroll
        for (int l = 0; l < BM / 32; ++l) {
            int r = w * (BM / 4) + l * 8;
            int gr = rowbase + r + rsub;
            if (gr >= NNODES) gr = NNODES - 1;
            const unsigned short* gp = Ab + (size_t)gr * Astr + kof + csw * 8;
            __builtin_amdgcn_global_load_lds(
                (const __attribute__((address_space(1))) void*)gp,
                (__attribute__((address_space(3))) void*)(As + r * BK), 16, 0, 0);
        }
#pragma unroll
        for (int l = 0; l < BN / 32; ++l) {
            int r = w * (BN / 4) + l * 8;
            const unsigned short* gp = Bt + (size_t)(colbase + r + rsub) * KDIM + kt + csw * 8;
            __builtin_amdgcn_global_load_lds(
                (const __attribute__((address_space(1))) void*)gp,
                (__attribute__((address_space(3))) void*)(Bs + r * BK), 16, 0, 0);
        }
        __syncthreads();
#pragma unroll
        for (int kk = 0; kk < BK; kk += 32) {
            const int kidx = (kk >> 3) + quad;
            const int phys = kidx ^ (lm & 7);
            bf16x8 af[WM], bfr[WN];
#pragma unroll
            for (int mi = 0; mi < WM; ++mi)
                af[mi] = __builtin_bit_cast(bf16x8,
                    *(const u32x4*)(As + (wrow + mi * 16 + lm) * BK + phys * 8));
#pragma unroll
            for (int ni = 0; ni < WN; ++ni)
                bfr[ni] = __builtin_bit_cast(bf16x8,
                    *(const u32x4*)(Bs + (wcol + ni * 16 + lm) * BK + phys * 8));
#pragma unroll
            for (int mi = 0; mi < WM; ++mi)
#pragma unroll
                for (int ni = 0; ni < WN; ++ni)
                    acc[mi][ni] = __builtin_amdgcn_mfma_f32_16x16x32_bf16(
                        af[mi], bfr[ni], acc[mi][ni], 0, 0, 0);
        }
        __syncthreads();
    }

#pragma unroll
    for (int ni = 0; ni < WN; ++ni) {
        int gc = colbase + wcol + ni * 16 + lm;
        float r1v = r1[gc], r2v = r2[gc], bv = bias[gc];
#pragma unroll
        for (int mi = 0; mi < WM; ++mi) {
#pragma unroll
            for (int r = 0; r < 4; ++r) {
                int grow = rowbase + wrow + mi * 16 + quad * 4 + r;
                if (grow < NNODES) {
                    float v = acc[mi][ni][r] + s1[grow] * r1v + (float)grow * r2v + bv;
                    v = (v >= 0.f) ? v : 0.01f * v;
                    if (OBF16)
                        ((unsigned short*)outp)[(size_t)grow * OSTRIDE + gc] = f2bf(v);
                    else
                        ((float*)outp)[(size_t)grow * OSTRIDE + gc] = v;
                }
            }
        }
    }
}

// ---------------- head ----------------
__global__ __launch_bounds__(64) void k_head(const float* __restrict__ h2,
                                             const float* __restrict__ Wp,
                                             const float* __restrict__ bp,
                                             const float* __restrict__ Wr,
                                             const float* __restrict__ br,
                                             float* __restrict__ out) {
    int n = blockIdx.x;
    int l = threadIdx.x;
    float v = h2[(size_t)n * 64 + l];
    float dots[7];
#pragma unroll
    for (int j = 0; j < 3; ++j) {
        float p = v * Wp[l * 3 + j];
#pragma unroll
        for (int off = 32; off; off >>= 1) p += __shfl_xor(p, off);
        dots[j] = p;
    }
#pragma unroll
    for (int j = 0; j < 4; ++j) {
        float p = v * Wr[l * 4 + j];
#pragma unroll
        for (int off = 32; off; off >>= 1) p += __shfl_xor(p, off);
        dots[3 + j] = p;
    }
    float idx = (float)n;
    float rot[4];
    float nrm = 0.f;
#pragma unroll
    for (int j = 0; j < 4; ++j) {
        rot[j] = dots[3 + j] + idx * Wr[64 * 4 + j] + br[j];
        nrm += rot[j] * rot[j];
    }
    nrm = fmaxf(sqrtf(nrm), 1e-12f);
    if (l < 3)
        out[n * 7 + l] = dots[l] + idx * Wp[64 * 3 + l] + bp[l];
    else if (l < 7)
        out[n * 7 + l] = rot[l - 3] / nrm;
}

extern "C" void kernel_launch(void* const* d_in, const int* in_sizes, int n_in,
                              void* d_out, int out_size, void* d_ws, size_t ws_size,
                              hipStream_t stream) {
    const float* x       = (const float*)d_in[0];
    const float* W1_rel  = (const float*)d_in[1];
    const float* b1      = (const float*)d_in[2];
    const float* W1_root = (const float*)d_in[3];
    const float* W2_rel  = (const float*)d_in[4];
    const float* b2      = (const float*)d_in[5];
    const float* W2_root = (const float*)d_in[6];
    const float* Wp      = (const float*)d_in[7];
    const float* bp      = (const float*)d_in[8];
    const float* Wr      = (const float*)d_in[9];
    const float* br      = (const float*)d_in[10];
    const int*   ei      = (const int*)d_in[11];
    float* out = (float*)d_out;

    char* ws = (char*)d_ws;
    size_t off = 0;
    auto alloc = [&](size_t bytes) {
        size_t o = off;
        off = (off + bytes + 255) & ~(size_t)255;
        return (void*)(ws + o);
    };
    int*   deg       = (int*)alloc(NNODES * 4);
    int*   cursor    = (int*)alloc(NNODES * 4);
    int*   row_start = (int*)alloc((NNODES + 1) * 4);
    int*   srcs      = (int*)alloc(NEDGES * 4);
    int*   partials  = (int*)alloc(NSCANB * 4);
    float* aggidx    = (float*)alloc(NNODES * 4);
    float* sidx      = (float*)alloc(NNODES * 4);
    unsigned short* xb     = (unsigned short*)alloc((size_t)NNODES * 512 * 2);
    unsigned short* AggBuf = (unsigned short*)alloc((size_t)NNODES * 512 * 2);
    unsigned short* H1     = (unsigned short*)alloc((size_t)NNODES * 256 * 2);
    unsigned short* Seg    = (unsigned short*)alloc((size_t)NNODES * 256 * 2);
    unsigned short* Bt1    = (unsigned short*)alloc(256 * 1024 * 2);
    unsigned short* Bt2    = (unsigned short*)alloc(64 * 512 * 2);
    float* h2        = (float*)alloc((size_t)NNODES * 64 * 4);

    hipMemsetAsync(deg, 0, NNODES * 4, stream);

    const int EB = (NEDGES + 255) / 256;
    k_count<<<EB, 256, 0, stream>>>(ei, deg);
    k_scanA<<<NSCANB, 256, 0, stream>>>(deg, row_start, partials);
    k_scanB<<<1, 256, 0, stream>>>(partials);
    k_scanC<<<NSCANB, 256, 0, stream>>>(row_start, partials, cursor);
    k_scatter<<<EB, 256, 0, stream>>>(ei, cursor, srcs);

    k_bt1<<<(256 * 1024) / 256, 256, 0, stream>>>(W1_rel, W1_root, Bt1);
    k_bt2<<<(64 * 512) / 256, 256, 0, stream>>>(W2_rel, W2_root, Bt2);

    k_xcastb<<<(NNODES * 64) / 256, 256, 0, stream>>>(x, xb);
    k_agg1<<<NNODES, 256, 0, stream>>>(xb, row_start, srcs, AggBuf);
    k_aggidx<<<NSCANB, 256, 0, stream>>>(row_start, srcs, aggidx, sidx);

    // GEMM1: [AggBuf | xb] @ Bt1^T -> H1 (bf16, stride 256)
    k_gemm<2, 2, 4, 4, 512, 1024, 512, 512, 256, true>
        <<<dim3((NNODES + 127) / 128, 2), 256, 0, stream>>>(
        AggBuf, xb, Bt1, aggidx, W1_rel + 512 * 256, W1_root + 512 * 256, b1, (void*)H1);

    k_agg2<<<NNODES / 2, 256, 0, stream>>>(row_start, srcs, H1, Seg);

    // GEMM2: [Seg | H1] @ Bt2^T -> h2 (f32, stride 64)
    k_gemm<4, 1, 2, 4, 256, 512, 256, 256, 64, false>
        <<<dim3((NNODES + 127) / 128, 1), 256, 0, stream>>>(
        Seg, H1, Bt2, sidx, W2_rel + 256 * 64, W2_root + 256 * 64, b2, (void*)h2);

    k_head<<<NNODES, 64, 0, stream>>>(h2, Wp, bp, Wr, br, out);
}

// Round 5
// 390.542 us; speedup vs baseline: 1.5783x; 1.1160x over previous
//
#include <hip/hip_runtime.h>

#define NNODES 50000
#define NEDGES 200000
#define NSCANB ((NNODES + 255) / 256)   // 196 scan blocks

typedef short  bf16x8 __attribute__((ext_vector_type(8)));
typedef float  f32x4  __attribute__((ext_vector_type(4)));
typedef unsigned int u32x4 __attribute__((ext_vector_type(4)));

__device__ __forceinline__ unsigned short f2bf(float f) {
    union { float f; unsigned int u; } c; c.f = f;
    unsigned int r = c.u + 0x7fffu + ((c.u >> 16) & 1u);
    return (unsigned short)(r >> 16);
}
__device__ __forceinline__ float bf2f(unsigned short h) {
    union { unsigned int u; float f; } c; c.u = ((unsigned int)h) << 16;
    return c.f;
}

// ---------------- fused prep: deg=0, Bt1, Bt2, x->bf16 ----------------
#define PREP_Z NNODES                 // zero deg
#define PREP_B1 (256 * 1024)          // Bt1 elements
#define PREP_B2 (64 * 512)            // Bt2 elements
#define PREP_XC (NNODES * 64)         // x cast chunks (8 elems each)
#define PREP_TOT (PREP_Z + PREP_B1 + PREP_B2 + PREP_XC)
__global__ __launch_bounds__(256) void k_prep(const float* __restrict__ x,
                                              const float* __restrict__ W1_rel,
                                              const float* __restrict__ W1_root,
                                              const float* __restrict__ W2_rel,
                                              const float* __restrict__ W2_root,
                                              int* __restrict__ deg,
                                              unsigned short* __restrict__ Bt1,
                                              unsigned short* __restrict__ Bt2,
                                              unsigned short* __restrict__ xb) {
    int i = blockIdx.x * 256 + threadIdx.x;
    if (i < PREP_Z) { deg[i] = 0; return; }
    i -= PREP_Z;
    if (i < PREP_B1) {
        int n = i >> 10, k = i & 1023;
        float v = (k < 512) ? W1_rel[k * 256 + n] : W1_root[(k - 512) * 256 + n];
        Bt1[i] = f2bf(v);
        return;
    }
    i -= PREP_B1;
    if (i < PREP_B2) {
        int n = i >> 9, k = i & 511;
        float v = (k < 256) ? W2_rel[k * 64 + n] : W2_root[(k - 256) * 64 + n];
        Bt2[i] = f2bf(v);
        return;
    }
    i -= PREP_B2;
    if (i < PREP_XC) {
        int n = i >> 6, c8 = (i & 63) * 8;
        const float* xp = x + (size_t)n * 512 + c8;
        float4 a = *(const float4*)xp;
        float4 b = *(const float4*)(xp + 4);
        unsigned short o[8];
        o[0] = f2bf(a.x); o[1] = f2bf(a.y); o[2] = f2bf(a.z); o[3] = f2bf(a.w);
        o[4] = f2bf(b.x); o[5] = f2bf(b.y); o[6] = f2bf(b.z); o[7] = f2bf(b.w);
        *(u32x4*)(xb + (size_t)n * 512 + c8) = *(const u32x4*)o;
    }
}

// ---------------- CSR build ----------------
__global__ void k_count(const int* __restrict__ ei, int* __restrict__ deg) {
    int e = blockIdx.x * 256 + threadIdx.x;
    if (e < NEDGES) atomicAdd(&deg[ei[NEDGES + e]], 1);
}

__global__ __launch_bounds__(256) void k_scanA(const int* __restrict__ deg,
                                               int* __restrict__ rs,
                                               int* __restrict__ partials) {
    __shared__ int sm[256];
    int t = threadIdx.x, i = blockIdx.x * 256 + t;
    int v = (i < NNODES) ? deg[i] : 0;
    sm[t] = v;
    __syncthreads();
#pragma unroll
    for (int off = 1; off < 256; off <<= 1) {
        int u = (t >= off) ? sm[t - off] : 0;
        __syncthreads();
        sm[t] += u;
        __syncthreads();
    }
    if (i < NNODES) rs[i] = sm[t] - v;
    if (t == 255) partials[blockIdx.x] = sm[255];
}

__global__ __launch_bounds__(256) void k_scanB(int* __restrict__ partials) {
    __shared__ int sm[256];
    int t = threadIdx.x;
    int v = (t < NSCANB) ? partials[t] : 0;
    sm[t] = v;
    __syncthreads();
#pragma unroll
    for (int off = 1; off < 256; off <<= 1) {
        int u = (t >= off) ? sm[t - off] : 0;
        __syncthreads();
        sm[t] += u;
        __syncthreads();
    }
    if (t < NSCANB) partials[t] = sm[t] - v;
}

__global__ __launch_bounds__(256) void k_scanC(int* __restrict__ rs,
                                               const int* __restrict__ partials,
                                               int* __restrict__ cursor) {
    int t = threadIdx.x, b = blockIdx.x, i = b * 256 + t;
    if (i < NNODES) {
        int v = rs[i] + partials[b];
        rs[i] = v;
        cursor[i] = v;
    }
    if (i == 0) rs[NNODES] = NEDGES;
}

__global__ void k_scatter(const int* __restrict__ ei, int* __restrict__ cursor,
                          int* __restrict__ srcs) {
    int e = blockIdx.x * 256 + threadIdx.x;
    if (e < NEDGES) {
        int d = ei[NEDGES + e];
        int p = atomicAdd(&cursor[d], 1);
        srcs[p] = ei[e];
    }
}

// ---------------- softmax aggregation (layer 1) + fused index aggregates ----
// block = one dst node; thread t handles cols 2t, 2t+1. Thread 0 additionally
// computes the index-column softmax (needs max-shift: values up to 5e4) and
// the plain index sum for layer 2.
__global__ __launch_bounds__(256) void k_agg1(const unsigned short* __restrict__ xb,
                                              const int* __restrict__ rs,
                                              const int* __restrict__ srcs,
                                              unsigned short* __restrict__ AggBuf,
                                              float* __restrict__ aggidx,
                                              float* __restrict__ sidx) {
    int n = blockIdx.x;
    int t = threadIdx.x;
    int e0 = rs[n], e1 = rs[n + 1];
    float d0 = 0.f, q0 = 0.f, d1 = 0.f, q1 = 0.f;
    float mI = -INFINITY, dI = 0.f, qI = 0.f, sI = 0.f;
    for (int e = e0; e < e1; ++e) {
        int s = srcs[e];
        unsigned int v = *(const unsigned int*)(xb + (size_t)s * 512 + t * 2);
        float v0 = bf2f((unsigned short)(v & 0xffffu));
        float v1 = bf2f((unsigned short)(v >> 16));
        float e0v = __expf(v0);
        float e1v = __expf(v1);
        d0 += e0v; q0 += e0v * v0;
        d1 += e1v; q1 += e1v * v1;
        if (t == 0) {
            float vi = (float)s;
            sI += vi;
            float nm = fmaxf(mI, vi);
            float sc = __expf(mI - nm), ee = __expf(vi - nm);
            dI = dI * sc + ee;
            qI = qI * sc + ee * vi;
            mI = nm;
        }
    }
    float a0 = q0 / fmaxf(d0, 1e-16f);
    float a1 = q1 / fmaxf(d1, 1e-16f);
    unsigned int o = (unsigned int)f2bf(a0) | ((unsigned int)f2bf(a1) << 16);
    *(unsigned int*)(AggBuf + (size_t)n * 512 + t * 2) = o;
    if (t == 0) {
        aggidx[n] = qI / fmaxf(dI, 1e-16f);
        sidx[n] = sI;
    }
}

// ---------------- sum aggregation (layer 2): 2 nodes per block ----------------
__global__ __launch_bounds__(256) void k_agg2(const int* __restrict__ rs,
                                              const int* __restrict__ srcs,
                                              const unsigned short* __restrict__ H1,
                                              unsigned short* __restrict__ Seg) {
    int half = threadIdx.x >> 7;
    int t = threadIdx.x & 127;
    int n = blockIdx.x * 2 + half;
    int e0 = rs[n], e1 = rs[n + 1];
    float a0 = 0.f, a1 = 0.f;
    for (int e = e0; e < e1; ++e) {
        int s = srcs[e];
        unsigned int v = *(const unsigned int*)(H1 + (size_t)s * 256 + t * 2);
        a0 += bf2f((unsigned short)(v & 0xffffu));
        a1 += bf2f((unsigned short)(v >> 16));
    }
    unsigned int o = (unsigned int)f2bf(a0) | ((unsigned int)f2bf(a1) << 16);
    *(unsigned int*)(Seg + (size_t)n * 256 + t * 2) = o;
}

// ---------------- GEMM1: 64x128 tile, split-A [AggBuf|xb], -> H1 bf16 -------
// 4 waves as 2x2; wave = 32 rows x 64 cols (WM=2, WN=4 of 16x16x32).
// LDS rows 64 shorts, chunk c of row r at c^(r&7). grid: (colblk=2, rowblk=782)
__global__ __launch_bounds__(256, 5) void k_gemm1(const unsigned short* __restrict__ A1,
                                                  const unsigned short* __restrict__ A2,
                                                  const unsigned short* __restrict__ Bt,
                                                  const float* __restrict__ s1,
                                                  const float* __restrict__ r1,
                                                  const float* __restrict__ r2,
                                                  const float* __restrict__ bias,
                                                  unsigned short* __restrict__ outp) {
    constexpr int BM = 64, BN = 128, BK = 64;
    __shared__ __align__(16) unsigned short As[BM * BK];
    __shared__ __align__(16) unsigned short Bs[BN * BK];

    const int tid = threadIdx.x;
    const int w = tid >> 6;
    const int lane = tid & 63;
    const int lm = lane & 15;
    const int quad = lane >> 4;
    const int wr = w >> 1;              // 0..1
    const int wc = w & 1;               // 0..1
    const int rowbase = blockIdx.y * BM;
    const int colbase = blockIdx.x * BN;
    const int wrow = wr * 32;
    const int wcol = wc * 64;

    const int rsub = lane >> 3;
    const int csw = (lane & 7) ^ rsub;

    f32x4 acc[2][4];
#pragma unroll
    for (int mi = 0; mi < 2; ++mi)
#pragma unroll
        for (int ni = 0; ni < 4; ++ni) acc[mi][ni] = (f32x4){0.f, 0.f, 0.f, 0.f};

    for (int kt = 0; kt < 1024; kt += BK) {
        const unsigned short* Ab = (kt < 512) ? A1 : A2;
        int kof = (kt < 512) ? kt : kt - 512;
#pragma unroll
        for (int l = 0; l < 2; ++l) {                 // A: 8 segments / 4 waves
            int r = w * 16 + l * 8;
            int gr = rowbase + r + rsub;
            if (gr >= NNODES) gr = NNODES - 1;
            const unsigned short* gp = Ab + (size_t)gr * 512 + kof + csw * 8;
            __builtin_amdgcn_global_load_lds(
                (const __attribute__((address_space(1))) void*)gp,
                (__attribute__((address_space(3))) void*)(As + r * BK), 16, 0, 0);
        }
#pragma unroll
        for (int l = 0; l < 4; ++l) {                 // B: 16 segments / 4 waves
            int r = w * 32 + l * 8;
            const unsigned short* gp = Bt + (size_t)(colbase + r + rsub) * 1024 + kt + csw * 8;
            __builtin_amdgcn_global_load_lds(
                (const __attribute__((address_space(1))) void*)gp,
                (__attribute__((address_space(3))) void*)(Bs + r * BK), 16, 0, 0);
        }
        __syncthreads();
#pragma unroll
        for (int kk = 0; kk < BK; kk += 32) {
            const int kidx = (kk >> 3) + quad;
            const int phys = kidx ^ (lm & 7);
            bf16x8 af[2], bfr[4];
#pragma unroll
            for (int mi = 0; mi < 2; ++mi)
                af[mi] = __builtin_bit_cast(bf16x8,
                    *(const u32x4*)(As + (wrow + mi * 16 + lm) * BK + phys * 8));
#pragma unroll
            for (int ni = 0; ni < 4; ++ni)
                bfr[ni] = __builtin_bit_cast(bf16x8,
                    *(const u32x4*)(Bs + (wcol + ni * 16 + lm) * BK + phys * 8));
#pragma unroll
            for (int mi = 0; mi < 2; ++mi)
#pragma unroll
                for (int ni = 0; ni < 4; ++ni)
                    acc[mi][ni] = __builtin_amdgcn_mfma_f32_16x16x32_bf16(
                        af[mi], bfr[ni], acc[mi][ni], 0, 0, 0);
        }
        __syncthreads();
    }

#pragma unroll
    for (int ni = 0; ni < 4; ++ni) {
        int gc = colbase + wcol + ni * 16 + lm;
        float r1v = r1[gc], r2v = r2[gc], bv = bias[gc];
#pragma unroll
        for (int mi = 0; mi < 2; ++mi) {
#pragma unroll
            for (int r = 0; r < 4; ++r) {
                int grow = rowbase + wrow + mi * 16 + quad * 4 + r;
                if (grow < NNODES) {
                    float v = acc[mi][ni][r] + s1[grow] * r1v + (float)grow * r2v + bv;
                    v = (v >= 0.f) ? v : 0.01f * v;
                    outp[(size_t)grow * 256 + gc] = f2bf(v);
                }
            }
        }
    }
}

// ---------------- GEMM2 + fused head: 64x64 tile, split-A [Seg|H1] ----------
// 4 waves stacked; wave = 16 rows x 64 cols (WM=1, WN=4). After the K-loop the
// epilogued h2 tile goes to LDS (stride 65) and threads 0..63 run the head.
__global__ __launch_bounds__(256) void k_gemm2h(const unsigned short* __restrict__ A1,
                                                const unsigned short* __restrict__ A2,
                                                const unsigned short* __restrict__ Bt,
                                                const float* __restrict__ s1,
                                                const float* __restrict__ r1,
                                                const float* __restrict__ r2,
                                                const float* __restrict__ bias,
                                                const float* __restrict__ Wp,
                                                const float* __restrict__ bp,
                                                const float* __restrict__ Wr,
                                                const float* __restrict__ br,
                                                float* __restrict__ out) {
    constexpr int BM = 64, BN = 64, BK = 64;
    __shared__ __align__(16) unsigned short As[BM * BK];
    __shared__ __align__(16) unsigned short Bs[BN * BK];
    __shared__ float h2t[BM * 65];

    const int tid = threadIdx.x;
    const int w = tid >> 6;
    const int lane = tid & 63;
    const int lm = lane & 15;
    const int quad = lane >> 4;
    const int rowbase = blockIdx.x * BM;
    const int wrow = w * 16;

    const int rsub = lane >> 3;
    const int csw = (lane & 7) ^ rsub;

    f32x4 acc[4];
#pragma unroll
    for (int ni = 0; ni < 4; ++ni) acc[ni] = (f32x4){0.f, 0.f, 0.f, 0.f};

    for (int kt = 0; kt < 512; kt += BK) {
        const unsigned short* Ab = (kt < 256) ? A1 : A2;
        int kof = (kt < 256) ? kt : kt - 256;
#pragma unroll
        for (int l = 0; l < 2; ++l) {
            int r = w * 16 + l * 8;
            int gr = rowbase + r + rsub;
            if (gr >= NNODES) gr = NNODES - 1;
            const unsigned short* gp = Ab + (size_t)gr * 256 + kof + csw * 8;
            __builtin_amdgcn_global_load_lds(
                (const __attribute__((address_space(1))) void*)gp,
                (__attribute__((address_space(3))) void*)(As + r * BK), 16, 0, 0);
        }
#pragma unroll
        for (int l = 0; l < 2; ++l) {
            int r = w * 16 + l * 8;
            const unsigned short* gp = Bt + (size_t)(r + rsub) * 512 + kt + csw * 8;
            __builtin_amdgcn_global_load_lds(
                (const __attribute__((address_space(1))) void*)gp,
                (__attribute__((address_space(3))) void*)(Bs + r * BK), 16, 0, 0);
        }
        __syncthreads();
#pragma unroll
        for (int kk = 0; kk < BK; kk += 32) {
            const int kidx = (kk >> 3) + quad;
            const int phys = kidx ^ (lm & 7);
            bf16x8 af;
            af = __builtin_bit_cast(bf16x8,
                *(const u32x4*)(As + (wrow + lm) * BK + phys * 8));
            bf16x8 bfr[4];
#pragma unroll
            for (int ni = 0; ni < 4; ++ni)
                bfr[ni] = __builtin_bit_cast(bf16x8,
                    *(const u32x4*)(Bs + (ni * 16 + lm) * BK + phys * 8));
#pragma unroll
            for (int ni = 0; ni < 4; ++ni)
                acc[ni] = __builtin_amdgcn_mfma_f32_16x16x32_bf16(
                    af, bfr[ni], acc[ni], 0, 0, 0);
        }
        __syncthreads();
    }

    // epilogue -> LDS h2 tile
#pragma unroll
    for (int ni = 0; ni < 4; ++ni) {
        int gc = ni * 16 + lm;
        float r1v = r1[gc], r2v = r2[gc], bv = bias[gc];
#pragma unroll
        for (int r = 0; r < 4; ++r) {
            int lrow = wrow + quad * 4 + r;
            int grow = rowbase + lrow;
            float v = acc[ni][r] + s1[grow < NNODES ? grow : 0] * r1v +
                      (float)grow * r2v + bv;
            v = (v >= 0.f) ? v : 0.01f * v;
            h2t[lrow * 65 + gc] = v;
        }
    }
    __syncthreads();

    // head: threads 0..63, one row each
    if (tid < BM) {
        int grow = rowbase + tid;
        if (grow < NNODES) {
            const float* hv = h2t + tid * 65;
            float idx = (float)grow;
            float p0 = 0.f, p1 = 0.f, p2 = 0.f;
            float r0 = 0.f, r1a = 0.f, r2a = 0.f, r3 = 0.f;
#pragma unroll 8
            for (int c = 0; c < 64; ++c) {
                float v = hv[c];
                p0 += v * Wp[c * 3 + 0];
                p1 += v * Wp[c * 3 + 1];
                p2 += v * Wp[c * 3 + 2];
                r0 += v * Wr[c * 4 + 0];
                r1a += v * Wr[c * 4 + 1];
                r2a += v * Wr[c * 4 + 2];
                r3 += v * Wr[c * 4 + 3];
            }
            p0 += idx * Wp[64 * 3 + 0] + bp[0];
            p1 += idx * Wp[64 * 3 + 1] + bp[1];
            p2 += idx * Wp[64 * 3 + 2] + bp[2];
            r0 += idx * Wr[64 * 4 + 0] + br[0];
            r1a += idx * Wr[64 * 4 + 1] + br[1];
            r2a += idx * Wr[64 * 4 + 2] + br[2];
            r3 += idx * Wr[64 * 4 + 3] + br[3];
            float nrm = fmaxf(sqrtf(r0 * r0 + r1a * r1a + r2a * r2a + r3 * r3), 1e-12f);
            float* op = out + (size_t)grow * 7;
            op[0] = p0; op[1] = p1; op[2] = p2;
            op[3] = r0 / nrm; op[4] = r1a / nrm; op[5] = r2a / nrm; op[6] = r3 / nrm;
        }
    }
}

extern "C" void kernel_launch(void* const* d_in, const int* in_sizes, int n_in,
                              void* d_out, int out_size, void* d_ws, size_t ws_size,
                              hipStream_t stream) {
    const float* x       = (const float*)d_in[0];
    const float* W1_rel  = (const float*)d_in[1];
    const float* b1      = (const float*)d_in[2];
    const float* W1_root = (const float*)d_in[3];
    const float* W2_rel  = (const float*)d_in[4];
    const float* b2      = (const float*)d_in[5];
    const float* W2_root = (const float*)d_in[6];
    const float* Wp      = (const float*)d_in[7];
    const float* bp      = (const float*)d_in[8];
    const float* Wr      = (const float*)d_in[9];
    const float* br      = (const float*)d_in[10];
    const int*   ei      = (const int*)d_in[11];
    float* out = (float*)d_out;

    char* ws = (char*)d_ws;
    size_t off = 0;
    auto alloc = [&](size_t bytes) {
        size_t o = off;
        off = (off + bytes + 255) & ~(size_t)255;
        return (void*)(ws + o);
    };
    int*   deg       = (int*)alloc(NNODES * 4);
    int*   cursor    = (int*)alloc(NNODES * 4);
    int*   row_start = (int*)alloc((NNODES + 1) * 4);
    int*   srcs      = (int*)alloc(NEDGES * 4);
    int*   partials  = (int*)alloc(NSCANB * 4);
    float* aggidx    = (float*)alloc(NNODES * 4);
    float* sidx      = (float*)alloc(NNODES * 4);
    unsigned short* xb     = (unsigned short*)alloc((size_t)NNODES * 512 * 2);
    unsigned short* AggBuf = (unsigned short*)alloc((size_t)NNODES * 512 * 2);
    unsigned short* H1     = (unsigned short*)alloc((size_t)NNODES * 256 * 2);
    unsigned short* Seg    = (unsigned short*)alloc((size_t)NNODES * 256 * 2);
    unsigned short* Bt1    = (unsigned short*)alloc(256 * 1024 * 2);
    unsigned short* Bt2    = (unsigned short*)alloc(64 * 512 * 2);

    const int EB = (NEDGES + 255) / 256;

    k_prep<<<(PREP_TOT + 255) / 256, 256, 0, stream>>>(
        x, W1_rel, W1_root, W2_rel, W2_root, deg, Bt1, Bt2, xb);

    k_count<<<EB, 256, 0, stream>>>(ei, deg);
    k_scanA<<<NSCANB, 256, 0, stream>>>(deg, row_start, partials);
    k_scanB<<<1, 256, 0, stream>>>(partials);
    k_scanC<<<NSCANB, 256, 0, stream>>>(row_start, partials, cursor);
    k_scatter<<<EB, 256, 0, stream>>>(ei, cursor, srcs);

    k_agg1<<<NNODES, 256, 0, stream>>>(xb, row_start, srcs, AggBuf, aggidx, sidx);

    // GEMM1: [AggBuf | xb] @ Bt1^T -> H1 (bf16, stride 256). grid (col, row)
    k_gemm1<<<dim3(2, (NNODES + 63) / 64), 256, 0, stream>>>(
        AggBuf, xb, Bt1, aggidx, W1_rel + 512 * 256, W1_root + 512 * 256, b1, H1);

    k_agg2<<<NNODES / 2, 256, 0, stream>>>(row_start, srcs, H1, Seg);

    // GEMM2 + head: [Seg | H1] @ Bt2^T -> out
    k_gemm2h<<<(NNODES + 63) / 64, 256, 0, stream>>>(
        Seg, H1, Bt2, sidx, W2_rel + 256 * 64, W2_root + 256 * 64, b2,
        Wp, bp, Wr, br, out);
}